// Round 1
// baseline (1525.657 us; speedup 1.0000x reference)
//
#include <hip/hip_runtime.h>
#include <hip/hip_bf16.h>
#include <math.h>

// Fixed problem shapes (from reference module constants)
#define B_    8
#define DIM_  768
#define NH_   6
#define NP_   4
#define DV_   384
#define DH_   64
#define HID_  192
#define NTOK_ 5376
#define LIN_  1024
#define HH_   32
#define WW_   32
#define MQ_   (B_ * NTOK_)   // 43008 query rows
#define MF_   (B_ * LIN_)    // 8192 feat rows

// ---------------------------------------------------------------------------
// block-wide sum over `nwaves` waves (blockDim.x = 64*nwaves)
__device__ __forceinline__ float block_sum_f(float v, float* red, int nwaves) {
#pragma unroll
  for (int o = 32; o > 0; o >>= 1) v += __shfl_down(v, o, 64);
  int wid = threadIdx.x >> 6;
  int lane = threadIdx.x & 63;
  if (lane == 0) red[wid] = v;
  __syncthreads();
  float s = 0.f;
  for (int i = 0; i < nwaves; ++i) s += red[i];
  __syncthreads();
  return s;
}

// ---------------------------------------------------------------------------
// Per-row LayerNorm statistics for a [rows x 768] fp32 matrix.
__global__ __launch_bounds__(256) void ln_stats(const float* __restrict__ X,
                                                float* __restrict__ mu,
                                                float* __restrict__ rstd) {
  __shared__ float red[4];
  const int row = blockIdx.x;
  const float* xr = X + (size_t)row * DIM_;
  const int t = threadIdx.x;
  float x0 = xr[t], x1 = xr[t + 256], x2 = xr[t + 512];
  float s = block_sum_f(x0 + x1 + x2, red, 4);
  float m = s * (1.f / 768.f);
  float d0 = x0 - m, d1 = x1 - m, d2 = x2 - m;
  float sq = block_sum_f(d0 * d0 + d1 * d1 + d2 * d2, red, 4);
  float var = sq * (1.f / 768.f);
  if (t == 0) {
    mu[row] = m;
    rstd[row] = rsqrtf(var + 1e-6f);
  }
}

// ---------------------------------------------------------------------------
// Tiled fp32 GEMM: C[M,N] = op(A)[M,K] @ Bw[K,N] + bias[N] (+ addend[M,N])
// op(A) optionally applies LayerNorm per-row using (mu, rstd, lng, lnb).
// BM=BN=64, BK=16, 256 threads, 4x4 microtile. M % 64 == 0, K % 16 == 0.
// N may be < 64*gridDim.y (guarded).
__global__ __launch_bounds__(256) void gemm_fused(
    const float* __restrict__ A, const float* __restrict__ Bw,
    const float* __restrict__ bias, const float* __restrict__ addend,
    const float* __restrict__ mu, const float* __restrict__ rstd,
    const float* __restrict__ lng, const float* __restrict__ lnb,
    float* __restrict__ C, int M, int N, int K) {
  __shared__ float As[16][68];
  __shared__ float Bs[16][68];
  const int bm = blockIdx.x * 64;
  const int bn = blockIdx.y * 64;
  const int t = threadIdx.x;
  const int ty = t >> 4, tx = t & 15;
  const int arow = t >> 2, ac4 = (t & 3) * 4;
  const int brow = t >> 4, bc4 = (t & 15) * 4;
  const bool do_ln = (mu != nullptr);
  float rmu = 0.f, rrs = 0.f;
  if (do_ln) {
    rmu = mu[bm + arow];
    rrs = rstd[bm + arow];
  }
  float acc[4][4] = {};
  for (int kt = 0; kt < K; kt += 16) {
    float4 av = *(const float4*)(A + (size_t)(bm + arow) * K + kt + ac4);
    if (do_ln) {
      float4 g4 = *(const float4*)(lng + kt + ac4);
      float4 b4 = *(const float4*)(lnb + kt + ac4);
      av.x = (av.x - rmu) * rrs * g4.x + b4.x;
      av.y = (av.y - rmu) * rrs * g4.y + b4.y;
      av.z = (av.z - rmu) * rrs * g4.z + b4.z;
      av.w = (av.w - rmu) * rrs * g4.w + b4.w;
    }
    As[ac4 + 0][arow] = av.x;
    As[ac4 + 1][arow] = av.y;
    As[ac4 + 2][arow] = av.z;
    As[ac4 + 3][arow] = av.w;
    float4 bv = make_float4(0.f, 0.f, 0.f, 0.f);
    if (bn + bc4 < N) bv = *(const float4*)(Bw + (size_t)(kt + brow) * N + bn + bc4);
    *(float4*)&Bs[brow][bc4] = bv;
    __syncthreads();
#pragma unroll
    for (int k = 0; k < 16; ++k) {
      float4 a4 = *(const float4*)&As[k][ty * 4];
      float4 b4 = *(const float4*)&Bs[k][tx * 4];
      acc[0][0] += a4.x * b4.x; acc[0][1] += a4.x * b4.y;
      acc[0][2] += a4.x * b4.z; acc[0][3] += a4.x * b4.w;
      acc[1][0] += a4.y * b4.x; acc[1][1] += a4.y * b4.y;
      acc[1][2] += a4.y * b4.z; acc[1][3] += a4.y * b4.w;
      acc[2][0] += a4.z * b4.x; acc[2][1] += a4.z * b4.y;
      acc[2][2] += a4.z * b4.z; acc[2][3] += a4.z * b4.w;
      acc[3][0] += a4.w * b4.x; acc[3][1] += a4.w * b4.y;
      acc[3][2] += a4.w * b4.z; acc[3][3] += a4.w * b4.w;
    }
    __syncthreads();
  }
#pragma unroll
  for (int i = 0; i < 4; ++i) {
    const int row = bm + ty * 4 + i;
#pragma unroll
    for (int j = 0; j < 4; ++j) {
      const int col = bn + tx * 4 + j;
      if (col < N) {
        const size_t o = (size_t)row * N + col;
        float vv = acc[i][j] + bias[col];
        if (addend) vv += addend[o];
        C[o] = vv;
      }
    }
  }
}

// ---------------------------------------------------------------------------
// loc = ref + off/32 (in-place on off buffer); softmax over NP=4 (in-place).
// One thread per (row, head).
__global__ __launch_bounds__(256) void loc_softmax(const float* __restrict__ ref,
                                                   float* __restrict__ offp,
                                                   float* __restrict__ attp) {
  const int i = blockIdx.x * 256 + threadIdx.x;
  if (i >= MQ_ * NH_) return;
  const int row = i / NH_, head = i % NH_;
  const float rx = ref[(size_t)row * 2 + 0];
  const float ry = ref[(size_t)row * 2 + 1];
  float* o = offp + (size_t)row * 48 + head * 8;
#pragma unroll
  for (int p = 0; p < 4; ++p) {
    o[p * 2 + 0] = rx + o[p * 2 + 0] * (1.f / 32.f);
    o[p * 2 + 1] = ry + o[p * 2 + 1] * (1.f / 32.f);
  }
  float* ap = attp + (size_t)row * 24 + head * 4;
  float l0 = ap[0], l1 = ap[1], l2 = ap[2], l3 = ap[3];
  float m = fmaxf(fmaxf(l0, l1), fmaxf(l2, l3));
  float e0 = expf(l0 - m), e1 = expf(l1 - m);
  float e2 = expf(l2 - m), e3 = expf(l3 - m);
  float s = 1.f / (e0 + e1 + e2 + e3);
  ap[0] = e0 * s; ap[1] = e1 * s; ap[2] = e2 * s; ap[3] = e3 * s;
}

// ---------------------------------------------------------------------------
// Bilinear sampling + attention-weight accumulation over P.
// Block = one (b, lq) token, 384 threads; wave w handles head w (64 channels).
__global__ __launch_bounds__(384) void msda_sample(const float* __restrict__ v,
                                                   const float* __restrict__ loc,
                                                   const float* __restrict__ aw,
                                                   float* __restrict__ outv) {
  __shared__ float sl[48];
  __shared__ float sa[24];
  const int row = blockIdx.x;  // b*NTOK + lq
  const int b = row / NTOK_;
  const int t = threadIdx.x;
  if (t < 48) sl[t] = loc[(size_t)row * 48 + t];
  else if (t < 72) sa[t - 48] = aw[(size_t)row * 24 + (t - 48)];
  __syncthreads();
  const int head = t >> 6, ch = t & 63;
  const float* vb = v + (size_t)b * LIN_ * DV_ + head * DH_ + ch;
  float acc = 0.f;
#pragma unroll
  for (int p = 0; p < NP_; ++p) {
    const float x = sl[head * 8 + p * 2 + 0] * (float)WW_ - 0.5f;
    const float y = sl[head * 8 + p * 2 + 1] * (float)HH_ - 0.5f;
    const float a = sa[head * 4 + p];
    const float x0f = floorf(x), y0f = floorf(y);
    const float wx = x - x0f, wy = y - y0f;
    const int x0 = (int)x0f, y0 = (int)y0f;
#pragma unroll
    for (int dy = 0; dy < 2; ++dy) {
      const int yi = y0 + dy;
      if ((unsigned)yi >= (unsigned)HH_) continue;
      const float wyy = dy ? wy : 1.f - wy;
#pragma unroll
      for (int dx = 0; dx < 2; ++dx) {
        const int xi = x0 + dx;
        if ((unsigned)xi >= (unsigned)WW_) continue;
        const float wxx = dx ? wx : 1.f - wx;
        acc += a * wxx * wyy * vb[(size_t)(yi * WW_ + xi) * DV_];
      }
    }
  }
  outv[(size_t)row * DV_ + t] = acc;
}

// ---------------------------------------------------------------------------
// 3-level depthwise 3x3 conv (SAME, zero-pad) + bias + exact GELU.
// One thread per (b, token, channel).
__global__ __launch_bounds__(256) void conv_gelu(const float* __restrict__ y1,
                                                 const float* __restrict__ dww,
                                                 const float* __restrict__ dwb,
                                                 float* __restrict__ y2) {
  const int i = blockIdx.x * 256 + threadIdx.x;
  if (i >= B_ * NTOK_ * HID_) return;
  const int c = i % HID_;
  const int tmp = i / HID_;
  const int tok = tmp % NTOK_;
  const int b = tmp / NTOK_;
  int base, LH, LW;
  if (tok < 4096)      { base = 0;    LH = 64; LW = 64; }
  else if (tok < 5120) { base = 4096; LH = 32; LW = 32; }
  else                 { base = 5120; LH = 16; LW = 16; }
  const int pos = tok - base;
  const int hh = pos / LW, ww = pos % LW;
  float z = dwb[c];
  const float* yb = y1 + ((size_t)b * NTOK_ + base) * HID_ + c;
#pragma unroll
  for (int ky = 0; ky < 3; ++ky) {
    const int yy = hh + ky - 1;
    if ((unsigned)yy >= (unsigned)LH) continue;
#pragma unroll
    for (int kx = 0; kx < 3; ++kx) {
      const int xx = ww + kx - 1;
      if ((unsigned)xx >= (unsigned)LW) continue;
      z += yb[(size_t)(yy * LW + xx) * HID_] * dww[(ky * 3 + kx) * HID_ + c];
    }
  }
  y2[i] = 0.5f * z * (1.f + erff(z * 0.70710678118654752f));
}

// ---------------------------------------------------------------------------
extern "C" void kernel_launch(void* const* d_in, const int* in_sizes, int n_in,
                              void* d_out, int out_size, void* d_ws, size_t ws_size,
                              hipStream_t stream) {
  const float* query  = (const float*)d_in[0];
  const float* ref    = (const float*)d_in[1];
  const float* feat   = (const float*)d_in[2];
  const float* qn_g   = (const float*)d_in[5];
  const float* qn_b   = (const float*)d_in[6];
  const float* fn_g   = (const float*)d_in[7];
  const float* fn_b   = (const float*)d_in[8];
  const float* W_off  = (const float*)d_in[9];
  const float* b_off  = (const float*)d_in[10];
  const float* W_attn = (const float*)d_in[11];
  const float* b_attn = (const float*)d_in[12];
  const float* W_val  = (const float*)d_in[13];
  const float* b_val  = (const float*)d_in[14];
  const float* W_out  = (const float*)d_in[15];
  const float* b_out  = (const float*)d_in[16];
  const float* ffn_g  = (const float*)d_in[17];
  const float* ffn_b  = (const float*)d_in[18];
  const float* fc1_w  = (const float*)d_in[19];
  const float* fc1_b  = (const float*)d_in[20];
  const float* dw_w   = (const float*)d_in[21];
  const float* dw_b   = (const float*)d_in[22];
  const float* fc2_w  = (const float*)d_in[23];
  const float* fc2_b  = (const float*)d_in[24];
  float* out = (float*)d_out;
  float* ws = (float*)d_ws;

  // Workspace layout (floats). Peak ~91.8 MB.
  float* v       = ws;                 // 8192*384          = 3,145,728
  float* offp    = ws + 3145728;       // 43008*48          = 2,064,384
  float* attp    = ws + 5210112;       // 43008*24          = 1,032,192
  float* attnvec = ws + 6242304;       // 43008*384         = 16,515,072
  float* y1      = attnvec;            // alias (attnvec dead after x GEMM)
  float* y2      = ws + 14499840;      // 43008*192         = 8,257,536
  float* stats   = ws + 22757376;      // LN stats
  float* mu_q = stats;            float* rs_q = stats + 43008;
  float* mu_f = stats + 86016;    float* rs_f = stats + 94208;
  float* mu_x = stats + 102400;   float* rs_x = stats + 145408;

  // 1) LN stats for query and feat
  ln_stats<<<MQ_, 256, 0, stream>>>(query, mu_q, rs_q);
  ln_stats<<<MF_, 256, 0, stream>>>(feat, mu_f, rs_f);

  // 2) v = LN(feat) @ W_val + b_val        [8192 x 384]
  gemm_fused<<<dim3(MF_ / 64, 6), 256, 0, stream>>>(
      feat, W_val, b_val, nullptr, mu_f, rs_f, fn_g, fn_b, v, MF_, 384, 768);

  // 3) off = LN(q) @ W_off + b_off         [43008 x 48]
  gemm_fused<<<dim3(MQ_ / 64, 1), 256, 0, stream>>>(
      query, W_off, b_off, nullptr, mu_q, rs_q, qn_g, qn_b, offp, MQ_, 48, 768);

  // 4) attn logits = LN(q) @ W_attn + b_attn  [43008 x 24]
  gemm_fused<<<dim3(MQ_ / 64, 1), 256, 0, stream>>>(
      query, W_attn, b_attn, nullptr, mu_q, rs_q, qn_g, qn_b, attp, MQ_, 24, 768);

  // 5) loc = ref + off/32 ; softmax(attn) — in-place
  loc_softmax<<<(MQ_ * NH_ + 255) / 256, 256, 0, stream>>>(ref, offp, attp);

  // 6) bilinear sample + weight            [43008 x 384]
  msda_sample<<<MQ_, 384, 0, stream>>>(v, offp, attp, attnvec);

  // 7) x = attnvec @ W_out + b_out + query -> d_out
  gemm_fused<<<dim3(MQ_ / 64, 12), 256, 0, stream>>>(
      attnvec, W_out, b_out, query, nullptr, nullptr, nullptr, nullptr,
      out, MQ_, 768, 384);

  // 8) LN stats for x
  ln_stats<<<MQ_, 256, 0, stream>>>(out, mu_x, rs_x);

  // 9) y1 = LN(x) @ fc1_w + fc1_b          [43008 x 192]
  gemm_fused<<<dim3(MQ_ / 64, 3), 256, 0, stream>>>(
      out, fc1_w, fc1_b, nullptr, mu_x, rs_x, ffn_g, ffn_b, y1, MQ_, 192, 768);

  // 10) depthwise conv + GELU -> y2
  conv_gelu<<<(B_ * NTOK_ * HID_ + 255) / 256, 256, 0, stream>>>(y1, dw_w, dw_b, y2);

  // 11) out = x + y2 @ fc2_w + fc2_b       (in-place epilogue on d_out)
  gemm_fused<<<dim3(MQ_ / 64, 12), 256, 0, stream>>>(
      y2, fc2_w, fc2_b, out, nullptr, nullptr, nullptr, nullptr,
      out, MQ_, 768, 192);
}

// Round 2
// 1011.982 us; speedup vs baseline: 1.5076x; 1.5076x over previous
//
#include <hip/hip_runtime.h>
#include <hip/hip_bf16.h>
#include <math.h>

// Fixed problem shapes
#define B_    8
#define DIM_  768
#define NH_   6
#define NP_   4
#define DV_   384
#define DH_   64
#define HID_  192
#define NTOK_ 5376
#define LIN_  1024
#define HH_   32
#define WW_   32
#define MQ_   (B_ * NTOK_)   // 43008
#define MF_   (B_ * LIN_)    // 8192

using fv4  = __attribute__((ext_vector_type(4))) float;
using bfv8 = __attribute__((ext_vector_type(8))) __bf16;
using sv8  = __attribute__((ext_vector_type(8))) short;

__device__ __forceinline__ short f2bf(float f) {
  union { float f; unsigned u; } v; v.f = f;
  unsigned r = v.u + 0x7FFFu + ((v.u >> 16) & 1u);   // RNE
  return (short)(r >> 16);
}
__device__ __forceinline__ float bf2f(short s) {
  union { unsigned u; float f; } v;
  v.u = ((unsigned)(unsigned short)s) << 16;
  return v.f;
}

// ---------------------------------------------------------------------------
__device__ __forceinline__ float block_sum_f(float v, float* red, int nwaves) {
#pragma unroll
  for (int o = 32; o > 0; o >>= 1) v += __shfl_down(v, o, 64);
  int wid = threadIdx.x >> 6;
  int lane = threadIdx.x & 63;
  if (lane == 0) red[wid] = v;
  __syncthreads();
  float s = 0.f;
  for (int i = 0; i < nwaves; ++i) s += red[i];
  __syncthreads();
  return s;
}

// ---------------------------------------------------------------------------
// LayerNorm applied and written as bf16 row [rows x 768].
__global__ __launch_bounds__(256) void ln_apply(const float* __restrict__ X,
                                                const float* __restrict__ g,
                                                const float* __restrict__ b,
                                                short* __restrict__ Y) {
  __shared__ float red[4];
  const int row = blockIdx.x;
  const float* xr = X + (size_t)row * DIM_;
  const int t = threadIdx.x;
  float x0 = xr[t], x1 = xr[t + 256], x2 = xr[t + 512];
  float s = block_sum_f(x0 + x1 + x2, red, 4);
  const float m = s * (1.f / 768.f);
  float d0 = x0 - m, d1 = x1 - m, d2 = x2 - m;
  float sq = block_sum_f(d0 * d0 + d1 * d1 + d2 * d2, red, 4);
  const float rs = rsqrtf(sq * (1.f / 768.f) + 1e-6f);
  short* yr = Y + (size_t)row * DIM_;
  yr[t]       = f2bf(d0 * rs * g[t]       + b[t]);
  yr[t + 256] = f2bf(d1 * rs * g[t + 256] + b[t + 256]);
  yr[t + 512] = f2bf(d2 * rs * g[t + 512] + b[t + 512]);
}

// ---------------------------------------------------------------------------
// Transpose-convert weight fp32 [K][N] -> bf16 [N][K] (row offset for concat).
__global__ __launch_bounds__(256) void tconv(const float* __restrict__ src,
                                             short* __restrict__ dst,
                                             int K, int N, int rowOff) {
  const int i = blockIdx.x * 256 + threadIdx.x;
  if (i >= K * N) return;
  const int n = i / K, k = i % K;
  dst[(size_t)(n + rowOff) * K + k] = f2bf(src[(size_t)k * N + n]);
}

// ---------------------------------------------------------------------------
// MFMA GEMM: C[M,N] = A[M,K](bf16) @ Bt[N,K](bf16)^T + bias (+ addend).
// BM=BN=128, BK=64, 256 threads (4 waves, 2x2 of 64x64), 16x16x32 bf16 MFMA.
// M%128==0, K%64==0; N tail guarded. Output fp32 (C) or bf16 (Cb).
__global__ __launch_bounds__(256) void gemm_mfma(
    const short* __restrict__ A, const short* __restrict__ Bt,
    const float* __restrict__ bias, const float* __restrict__ addend,
    float* __restrict__ C, short* __restrict__ Cb,
    int M, int N, int K) {
  __shared__ short As[128 * 72];   // 64 cols + 8 pad (bank-conflict-free reads)
  __shared__ short Bs[128 * 72];
  const int bm = blockIdx.x * 128;
  const int bn = blockIdx.y * 128;
  const int t = threadIdx.x;
  const int lane = t & 63;
  const int wid = t >> 6;
  const int wr = (wid >> 1) * 64;
  const int wc = (wid & 1) * 64;
  const int l15 = lane & 15;
  const int kgrp = (lane >> 4) * 8;

  fv4 acc[4][4] = {};

  for (int kt = 0; kt < K; kt += 64) {
#pragma unroll
    for (int i = 0; i < 4; ++i) {
      const int chunk = i * 256 + t;       // 1024 chunks of 8 bf16
      const int r = chunk >> 3;
      const int c = (chunk & 7) << 3;
      *(sv8*)&As[r * 72 + c] = *(const sv8*)&A[(size_t)(bm + r) * K + kt + c];
      sv8 bv = {};
      if (bn + r < N) bv = *(const sv8*)&Bt[(size_t)(bn + r) * K + kt + c];
      *(sv8*)&Bs[r * 72 + c] = bv;
    }
    __syncthreads();
#pragma unroll
    for (int kk = 0; kk < 64; kk += 32) {
      bfv8 af[4], bf[4];
#pragma unroll
      for (int m = 0; m < 4; ++m)
        af[m] = *(const bfv8*)&As[(wr + m * 16 + l15) * 72 + kk + kgrp];
#pragma unroll
      for (int n = 0; n < 4; ++n)
        bf[n] = *(const bfv8*)&Bs[(wc + n * 16 + l15) * 72 + kk + kgrp];
#pragma unroll
      for (int m = 0; m < 4; ++m)
#pragma unroll
        for (int n = 0; n < 4; ++n)
          acc[m][n] = __builtin_amdgcn_mfma_f32_16x16x32_bf16(
              af[m], bf[n], acc[m][n], 0, 0, 0);
    }
    __syncthreads();
  }

  // C/D layout (verified): col = lane&15, row = (lane>>4)*4 + reg
  const int r0 = bm + wr + (lane >> 4) * 4;
  const int c0 = bn + wc + l15;
#pragma unroll
  for (int n = 0; n < 4; ++n) {
    const int col = c0 + n * 16;
    if (col >= N) continue;
    const float bv = bias ? bias[col] : 0.f;
#pragma unroll
    for (int m = 0; m < 4; ++m) {
#pragma unroll
      for (int j = 0; j < 4; ++j) {
        const int row = r0 + m * 16 + j;
        const size_t o = (size_t)row * N + col;
        float vv = acc[m][n][j] + bv;
        if (addend) vv += addend[o];
        if (C) C[o] = vv;
        else   Cb[o] = f2bf(vv);
      }
    }
  }
}

// ---------------------------------------------------------------------------
// oa row layout: [48 off | 24 attn], fp32, stride 72.
// loc = ref + (off + b_off)/32 ; softmax(attn + b_attn) over NP=4. In-place.
__global__ __launch_bounds__(256) void loc_softmax(
    const float* __restrict__ ref, const float* __restrict__ boff,
    const float* __restrict__ battn, float* __restrict__ oa) {
  const int i = blockIdx.x * 256 + threadIdx.x;
  if (i >= MQ_ * NH_) return;
  const int row = i / NH_, head = i % NH_;
  const float rx = ref[(size_t)row * 2 + 0];
  const float ry = ref[(size_t)row * 2 + 1];
  float* o = oa + (size_t)row * 72 + head * 8;
#pragma unroll
  for (int p = 0; p < 4; ++p) {
    o[p * 2 + 0] = rx + (o[p * 2 + 0] + boff[head * 8 + p * 2 + 0]) * (1.f / 32.f);
    o[p * 2 + 1] = ry + (o[p * 2 + 1] + boff[head * 8 + p * 2 + 1]) * (1.f / 32.f);
  }
  float* ap = oa + (size_t)row * 72 + 48 + head * 4;
  float l0 = ap[0] + battn[head * 4 + 0];
  float l1 = ap[1] + battn[head * 4 + 1];
  float l2 = ap[2] + battn[head * 4 + 2];
  float l3 = ap[3] + battn[head * 4 + 3];
  float mx = fmaxf(fmaxf(l0, l1), fmaxf(l2, l3));
  float e0 = expf(l0 - mx), e1 = expf(l1 - mx);
  float e2 = expf(l2 - mx), e3 = expf(l3 - mx);
  float sinv = 1.f / (e0 + e1 + e2 + e3);
  ap[0] = e0 * sinv; ap[1] = e1 * sinv; ap[2] = e2 * sinv; ap[3] = e3 * sinv;
}

// ---------------------------------------------------------------------------
// Bilinear sampling + attention accumulation; v is bf16, output bf16.
// Block = one token, 384 threads; wave w -> head w (64 channels).
__global__ __launch_bounds__(384) void msda_sample(const short* __restrict__ v,
                                                   const float* __restrict__ oa,
                                                   short* __restrict__ outv) {
  __shared__ float sl[48];
  __shared__ float sa[24];
  const int row = blockIdx.x;
  const int b = row / NTOK_;
  const int t = threadIdx.x;
  if (t < 48) sl[t] = oa[(size_t)row * 72 + t];
  else if (t < 72) sa[t - 48] = oa[(size_t)row * 72 + t];
  __syncthreads();
  const int head = t >> 6, ch = t & 63;
  const short* vb = v + (size_t)b * LIN_ * DV_ + head * DH_ + ch;
  float acc = 0.f;
#pragma unroll
  for (int p = 0; p < NP_; ++p) {
    const float x = sl[head * 8 + p * 2 + 0] * (float)WW_ - 0.5f;
    const float y = sl[head * 8 + p * 2 + 1] * (float)HH_ - 0.5f;
    const float a = sa[head * 4 + p];
    const float x0f = floorf(x), y0f = floorf(y);
    const float wx = x - x0f, wy = y - y0f;
    const int x0 = (int)x0f, y0 = (int)y0f;
#pragma unroll
    for (int dy = 0; dy < 2; ++dy) {
      const int yi = y0 + dy;
      if ((unsigned)yi >= (unsigned)HH_) continue;
      const float wyy = dy ? wy : 1.f - wy;
#pragma unroll
      for (int dx = 0; dx < 2; ++dx) {
        const int xi = x0 + dx;
        if ((unsigned)xi >= (unsigned)WW_) continue;
        const float wxx = dx ? wx : 1.f - wx;
        acc += a * wxx * wyy * bf2f(vb[(size_t)(yi * WW_ + xi) * DV_]);
      }
    }
  }
  outv[(size_t)row * DV_ + t] = f2bf(acc);
}

// ---------------------------------------------------------------------------
// Depthwise 3x3 (3-level pyramid, SAME zero-pad) + bias + exact GELU -> bf16.
__global__ __launch_bounds__(256) void conv_gelu(const float* __restrict__ y1,
                                                 const float* __restrict__ dww,
                                                 const float* __restrict__ dwb,
                                                 short* __restrict__ y2) {
  const int i = blockIdx.x * 256 + threadIdx.x;
  if (i >= B_ * NTOK_ * HID_) return;
  const int c = i % HID_;
  const int tmp = i / HID_;
  const int tok = tmp % NTOK_;
  const int b = tmp / NTOK_;
  int base, LH, LW;
  if (tok < 4096)      { base = 0;    LH = 64; LW = 64; }
  else if (tok < 5120) { base = 4096; LH = 32; LW = 32; }
  else                 { base = 5120; LH = 16; LW = 16; }
  const int pos = tok - base;
  const int hh = pos / LW, ww = pos % LW;
  float z = dwb[c];
  const float* yb = y1 + ((size_t)b * NTOK_ + base) * HID_ + c;
#pragma unroll
  for (int ky = 0; ky < 3; ++ky) {
    const int yy = hh + ky - 1;
    if ((unsigned)yy >= (unsigned)LH) continue;
#pragma unroll
    for (int kx = 0; kx < 3; ++kx) {
      const int xx = ww + kx - 1;
      if ((unsigned)xx >= (unsigned)LW) continue;
      z += yb[(size_t)(yy * LW + xx) * HID_] * dww[(ky * 3 + kx) * HID_ + c];
    }
  }
  y2[i] = f2bf(0.5f * z * (1.f + erff(z * 0.70710678118654752f)));
}

// ---------------------------------------------------------------------------
extern "C" void kernel_launch(void* const* d_in, const int* in_sizes, int n_in,
                              void* d_out, int out_size, void* d_ws, size_t ws_size,
                              hipStream_t stream) {
  const float* query  = (const float*)d_in[0];
  const float* ref    = (const float*)d_in[1];
  const float* feat   = (const float*)d_in[2];
  const float* qn_g   = (const float*)d_in[5];
  const float* qn_b   = (const float*)d_in[6];
  const float* fn_g   = (const float*)d_in[7];
  const float* fn_b   = (const float*)d_in[8];
  const float* W_off  = (const float*)d_in[9];
  const float* b_off  = (const float*)d_in[10];
  const float* W_attn = (const float*)d_in[11];
  const float* b_attn = (const float*)d_in[12];
  const float* W_val  = (const float*)d_in[13];
  const float* b_val  = (const float*)d_in[14];
  const float* W_out  = (const float*)d_in[15];
  const float* b_out  = (const float*)d_in[16];
  const float* ffn_g  = (const float*)d_in[17];
  const float* ffn_b  = (const float*)d_in[18];
  const float* fc1_w  = (const float*)d_in[19];
  const float* fc1_b  = (const float*)d_in[20];
  const float* dw_w   = (const float*)d_in[21];
  const float* dw_b   = (const float*)d_in[22];
  const float* fc2_w  = (const float*)d_in[23];
  const float* fc2_b  = (const float*)d_in[24];
  float* out = (float*)d_out;
  char* wsb = (char*)d_ws;

  // Workspace layout (bytes, 16B-aligned). Total ~136 MB.
  short* qn_xn = (short*)(wsb + 0);           // 43008*768 bf16 (qn, later xn)
  short* vbf   = (short*)(wsb + 66060288);    // 8192*384 bf16
  float* oa    = (float*)(wsb + 72351744);    // 43008*72 fp32
  short* attnv = (short*)(wsb + 84738048);    // 43008*384 bf16
  float* y1    = (float*)(wsb + 84738048);    // alias (attnv dead) 43008*192 f32
  short* fnb   = (short*)(wsb + 117768192);   // 8192*768 bf16
  short* y2    = (short*)(wsb + 117768192);   // alias (fnb dead) 43008*192 bf16
  short* vt    = (short*)(wsb + 134283264);   // W_val^T  [384][768]
  short* oat   = (short*)(wsb + 134873088);   // [Woff|Wattn]^T [72][768]
  short* ot    = (short*)(wsb + 134983680);   // W_out^T  [768][384]
  short* f1t   = (short*)(wsb + 135573504);   // fc1^T    [192][768]
  short* f2t   = (short*)(wsb + 135868416);   // fc2^T    [768][192]

  // Weight transpose+convert (tiny)
  tconv<<<(768 * 384 + 255) / 256, 256, 0, stream>>>(W_val, vt, 768, 384, 0);
  tconv<<<(768 * 48 + 255) / 256, 256, 0, stream>>>(W_off, oat, 768, 48, 0);
  tconv<<<(768 * 24 + 255) / 256, 256, 0, stream>>>(W_attn, oat, 768, 24, 48);
  tconv<<<(384 * 768 + 255) / 256, 256, 0, stream>>>(W_out, ot, 384, 768, 0);
  tconv<<<(768 * 192 + 255) / 256, 256, 0, stream>>>(fc1_w, f1t, 768, 192, 0);
  tconv<<<(192 * 768 + 255) / 256, 256, 0, stream>>>(fc2_w, f2t, 192, 768, 0);

  // LN -> bf16
  ln_apply<<<MQ_, 256, 0, stream>>>(query, qn_g, qn_b, qn_xn);
  ln_apply<<<MF_, 256, 0, stream>>>(feat, fn_g, fn_b, fnb);

  // v = LN(feat) @ W_val + b_val  -> bf16 [8192 x 384]
  gemm_mfma<<<dim3(MF_ / 128, 3), 256, 0, stream>>>(
      fnb, vt, b_val, nullptr, nullptr, vbf, MF_, 384, 768);

  // [off|attn] = LN(q) @ [W_off|W_attn]  (biases folded into loc_softmax)
  gemm_mfma<<<dim3(MQ_ / 128, 1), 256, 0, stream>>>(
      qn_xn, oat, nullptr, nullptr, oa, nullptr, MQ_, 72, 768);

  loc_softmax<<<(MQ_ * NH_ + 255) / 256, 256, 0, stream>>>(ref, b_off, b_attn, oa);

  msda_sample<<<MQ_, 384, 0, stream>>>(vbf, oa, attnv);

  // x = attnv @ W_out + b_out + query -> d_out (fp32)
  gemm_mfma<<<dim3(MQ_ / 128, 6), 256, 0, stream>>>(
      attnv, ot, b_out, query, out, nullptr, MQ_, 768, 384);

  // xn = LN(x) bf16 (reuse qn buffer)
  ln_apply<<<MQ_, 256, 0, stream>>>(out, ffn_g, ffn_b, qn_xn);

  // y1 = xn @ fc1 + fc1_b (fp32, feeds conv)
  gemm_mfma<<<dim3(MQ_ / 128, 2), 256, 0, stream>>>(
      qn_xn, f1t, fc1_b, nullptr, y1, nullptr, MQ_, 192, 768);

  conv_gelu<<<(MQ_ * HID_ + 255) / 256, 256, 0, stream>>>(y1, dw_w, dw_b, y2);

  // out = x + y2 @ fc2 + fc2_b (in-place epilogue on d_out)
  gemm_mfma<<<dim3(MQ_ / 128, 6), 256, 0, stream>>>(
      y2, f2t, fc2_b, out, out, nullptr, MQ_, 768, 192);
}

// Round 3
// 884.682 us; speedup vs baseline: 1.7245x; 1.1439x over previous
//
#include <hip/hip_runtime.h>
#include <hip/hip_bf16.h>
#include <math.h>

// Fixed problem shapes
#define B_    8
#define DIM_  768
#define NH_   6
#define NP_   4
#define DV_   384
#define DH_   64
#define HID_  192
#define NTOK_ 5376
#define LIN_  1024
#define HH_   32
#define WW_   32
#define MQ_   (B_ * NTOK_)   // 43008
#define MF_   (B_ * LIN_)    // 8192

using fv4  = __attribute__((ext_vector_type(4))) float;
using bfv8 = __attribute__((ext_vector_type(8))) __bf16;
using sv8  = __attribute__((ext_vector_type(8))) short;
using sv4  = __attribute__((ext_vector_type(4))) short;

__device__ __forceinline__ short f2bf(float f) {
  union { float f; unsigned u; } v; v.f = f;
  unsigned r = v.u + 0x7FFFu + ((v.u >> 16) & 1u);   // RNE
  return (short)(r >> 16);
}
__device__ __forceinline__ float bf2f(short s) {
  union { unsigned u; float f; } v;
  v.u = ((unsigned)(unsigned short)s) << 16;
  return v.f;
}

// ---------------------------------------------------------------------------
__device__ __forceinline__ float block_sum_f(float v, float* red, int nwaves) {
#pragma unroll
  for (int o = 32; o > 0; o >>= 1) v += __shfl_down(v, o, 64);
  int wid = threadIdx.x >> 6;
  int lane = threadIdx.x & 63;
  if (lane == 0) red[wid] = v;
  __syncthreads();
  float s = 0.f;
  for (int i = 0; i < nwaves; ++i) s += red[i];
  __syncthreads();
  return s;
}

// ---------------------------------------------------------------------------
// LayerNorm applied and written as bf16 row [rows x 768].
__global__ __launch_bounds__(256) void ln_apply(const float* __restrict__ X,
                                                const float* __restrict__ g,
                                                const float* __restrict__ b,
                                                short* __restrict__ Y) {
  __shared__ float red[4];
  const int row = blockIdx.x;
  const float* xr = X + (size_t)row * DIM_;
  const int t = threadIdx.x;
  float x0 = xr[t], x1 = xr[t + 256], x2 = xr[t + 512];
  float s = block_sum_f(x0 + x1 + x2, red, 4);
  const float m = s * (1.f / 768.f);
  float d0 = x0 - m, d1 = x1 - m, d2 = x2 - m;
  float sq = block_sum_f(d0 * d0 + d1 * d1 + d2 * d2, red, 4);
  const float rs = rsqrtf(sq * (1.f / 768.f) + 1e-6f);
  short* yr = Y + (size_t)row * DIM_;
  yr[t]       = f2bf(d0 * rs * g[t]       + b[t]);
  yr[t + 256] = f2bf(d1 * rs * g[t + 256] + b[t + 256]);
  yr[t + 512] = f2bf(d2 * rs * g[t + 512] + b[t + 512]);
}

// ---------------------------------------------------------------------------
// Transpose-convert weight fp32 [K][N] -> bf16 [N][K] (row offset for concat).
__global__ __launch_bounds__(256) void tconv(const float* __restrict__ src,
                                             short* __restrict__ dst,
                                             int K, int N, int rowOff) {
  const int i = blockIdx.x * 256 + threadIdx.x;
  if (i >= K * N) return;
  const int n = i / K, k = i % K;
  dst[(size_t)(n + rowOff) * K + k] = f2bf(src[(size_t)k * N + n]);
}

// ---------------------------------------------------------------------------
// MFMA GEMM: C[M,N] = A[M,K](bf16) @ Bt[N,K](bf16)^T + bias (+ addend).
// BM=BN=128, BK=64, 256 threads (4 waves, 2x2 of 64x64), 16x16x32 bf16 MFMA.
__global__ __launch_bounds__(256) void gemm_mfma(
    const short* __restrict__ A, const short* __restrict__ Bt,
    const float* __restrict__ bias, const float* __restrict__ addend,
    float* __restrict__ C, short* __restrict__ Cb,
    int M, int N, int K) {
  __shared__ short As[128 * 72];   // 64 cols + 8 pad
  __shared__ short Bs[128 * 72];
  const int bm = blockIdx.x * 128;
  const int bn = blockIdx.y * 128;
  const int t = threadIdx.x;
  const int lane = t & 63;
  const int wid = t >> 6;
  const int wr = (wid >> 1) * 64;
  const int wc = (wid & 1) * 64;
  const int l15 = lane & 15;
  const int kgrp = (lane >> 4) * 8;

  fv4 acc[4][4] = {};

  for (int kt = 0; kt < K; kt += 64) {
#pragma unroll
    for (int i = 0; i < 4; ++i) {
      const int chunk = i * 256 + t;       // 1024 chunks of 8 bf16
      const int r = chunk >> 3;
      const int c = (chunk & 7) << 3;
      *(sv8*)&As[r * 72 + c] = *(const sv8*)&A[(size_t)(bm + r) * K + kt + c];
      sv8 bv = {};
      if (bn + r < N) bv = *(const sv8*)&Bt[(size_t)(bn + r) * K + kt + c];
      *(sv8*)&Bs[r * 72 + c] = bv;
    }
    __syncthreads();
#pragma unroll
    for (int kk = 0; kk < 64; kk += 32) {
      bfv8 af[4], bf[4];
#pragma unroll
      for (int m = 0; m < 4; ++m)
        af[m] = *(const bfv8*)&As[(wr + m * 16 + l15) * 72 + kk + kgrp];
#pragma unroll
      for (int n = 0; n < 4; ++n)
        bf[n] = *(const bfv8*)&Bs[(wc + n * 16 + l15) * 72 + kk + kgrp];
#pragma unroll
      for (int m = 0; m < 4; ++m)
#pragma unroll
        for (int n = 0; n < 4; ++n)
          acc[m][n] = __builtin_amdgcn_mfma_f32_16x16x32_bf16(
              af[m], bf[n], acc[m][n], 0, 0, 0);
    }
    __syncthreads();
  }

  const int r0 = bm + wr + (lane >> 4) * 4;
  const int c0 = bn + wc + l15;
#pragma unroll
  for (int n = 0; n < 4; ++n) {
    const int col = c0 + n * 16;
    if (col >= N) continue;
    const float bv = bias ? bias[col] : 0.f;
#pragma unroll
    for (int m = 0; m < 4; ++m) {
#pragma unroll
      for (int j = 0; j < 4; ++j) {
        const int row = r0 + m * 16 + j;
        const size_t o = (size_t)row * N + col;
        float vv = acc[m][n][j] + bv;
        if (addend) vv += addend[o];
        if (C) C[o] = vv;
        else   Cb[o] = f2bf(vv);
      }
    }
  }
}

// ---------------------------------------------------------------------------
// prep_taps: one thread per (token,head). Applies offset/attn biases, builds
// sampling grid, softmax, and emits 16 (element_offset, weight) pairs.
// taps[i] layout: 16 x {int off_elems; float w} = 128 B, i = row*NH + head.
__global__ __launch_bounds__(256) void prep_taps(
    const float* __restrict__ ref, const float* __restrict__ boff,
    const float* __restrict__ battn, const float* __restrict__ oa,
    int* __restrict__ taps) {
  const int i = blockIdx.x * 256 + threadIdx.x;
  if (i >= MQ_ * NH_) return;
  const int row = i / NH_, head = i % NH_;
  const float rx = ref[(size_t)row * 2 + 0];
  const float ry = ref[(size_t)row * 2 + 1];
  const float* o = oa + (size_t)row * 72 + head * 8;
  const float* ap = oa + (size_t)row * 72 + 48 + head * 4;
  // softmax over 4 points
  float l0 = ap[0] + battn[head * 4 + 0];
  float l1 = ap[1] + battn[head * 4 + 1];
  float l2 = ap[2] + battn[head * 4 + 2];
  float l3 = ap[3] + battn[head * 4 + 3];
  float mx = fmaxf(fmaxf(l0, l1), fmaxf(l2, l3));
  float e0 = expf(l0 - mx), e1 = expf(l1 - mx);
  float e2 = expf(l2 - mx), e3 = expf(l3 - mx);
  float sinv = 1.f / (e0 + e1 + e2 + e3);
  float aw[4] = {e0 * sinv, e1 * sinv, e2 * sinv, e3 * sinv};

  int st[32];
  int k = 0;
#pragma unroll
  for (int p = 0; p < 4; ++p) {
    const float lx = rx + (o[p * 2 + 0] + boff[head * 8 + p * 2 + 0]) * (1.f / 32.f);
    const float ly = ry + (o[p * 2 + 1] + boff[head * 8 + p * 2 + 1]) * (1.f / 32.f);
    const float x = lx * (float)WW_ - 0.5f;
    const float y = ly * (float)HH_ - 0.5f;
    const float x0f = floorf(x), y0f = floorf(y);
    const float wx = x - x0f, wy = y - y0f;
    const int x0 = (int)x0f, y0 = (int)y0f;
    const float a = aw[p];
#pragma unroll
    for (int dy = 0; dy < 2; ++dy) {
      const int yi = y0 + dy;
      const float wyy = dy ? wy : 1.f - wy;
#pragma unroll
      for (int dx = 0; dx < 2; ++dx) {
        const int xi = x0 + dx;
        const float wxx = dx ? wx : 1.f - wx;
        const bool valid = ((unsigned)xi < (unsigned)WW_) & ((unsigned)yi < (unsigned)HH_);
        const int xc = min(max(xi, 0), WW_ - 1);
        const int yc = min(max(yi, 0), HH_ - 1);
        st[k++] = (yc * WW_ + xc) * DV_;
        float w = a * wxx * wyy;
        st[k++] = __float_as_int(valid ? w : 0.f);
      }
    }
  }
  int4* dst = (int4*)(taps + (size_t)i * 32);
#pragma unroll
  for (int j = 0; j < 8; ++j)
    dst[j] = make_int4(st[4 * j], st[4 * j + 1], st[4 * j + 2], st[4 * j + 3]);
}

// ---------------------------------------------------------------------------
// Gather + weighted accumulate. Thread = (token,head, 4 channels).
// 16 lanes per (token,head); ushort4 loads (128 B contiguous per group).
__global__ __launch_bounds__(256) void msda_sample2(const short* __restrict__ v,
                                                    const int* __restrict__ taps,
                                                    short* __restrict__ outv) {
  const int gid = blockIdx.x * 256 + threadIdx.x;   // exactly MQ_*NH_*16
  const int pair = gid >> 4;
  const int ch0 = (gid & 15) * 4;
  const int row = pair / NH_;
  const int head = pair - row * NH_;
  const int b = row / NTOK_;
  const short* vb = v + (size_t)b * LIN_ * DV_ + head * DH_ + ch0;
  const int4* tp = (const int4*)(taps + (size_t)pair * 32);
  float a0 = 0.f, a1 = 0.f, a2 = 0.f, a3 = 0.f;
#pragma unroll
  for (int j = 0; j < 8; ++j) {
    int4 pr = tp[j];
    {
      sv4 val = *(const sv4*)&vb[pr.x];
      const float w = __int_as_float(pr.y);
      a0 += w * bf2f(val[0]); a1 += w * bf2f(val[1]);
      a2 += w * bf2f(val[2]); a3 += w * bf2f(val[3]);
    }
    {
      sv4 val = *(const sv4*)&vb[pr.z];
      const float w = __int_as_float(pr.w);
      a0 += w * bf2f(val[0]); a1 += w * bf2f(val[1]);
      a2 += w * bf2f(val[2]); a3 += w * bf2f(val[3]);
    }
  }
  sv4 r;
  r[0] = f2bf(a0); r[1] = f2bf(a1); r[2] = f2bf(a2); r[3] = f2bf(a3);
  *(sv4*)&outv[(size_t)gid * 4] = r;
}

// ---------------------------------------------------------------------------
// Depthwise 3x3 (3-level pyramid, SAME zero-pad) + bias + exact GELU -> bf16.
__global__ __launch_bounds__(256) void conv_gelu(const float* __restrict__ y1,
                                                 const float* __restrict__ dww,
                                                 const float* __restrict__ dwb,
                                                 short* __restrict__ y2) {
  const int i = blockIdx.x * 256 + threadIdx.x;
  if (i >= B_ * NTOK_ * HID_) return;
  const int c = i % HID_;
  const int tmp = i / HID_;
  const int tok = tmp % NTOK_;
  const int b = tmp / NTOK_;
  int base, LH, LW;
  if (tok < 4096)      { base = 0;    LH = 64; LW = 64; }
  else if (tok < 5120) { base = 4096; LH = 32; LW = 32; }
  else                 { base = 5120; LH = 16; LW = 16; }
  const int pos = tok - base;
  const int hh = pos / LW, ww = pos % LW;
  float z = dwb[c];
  const float* yb = y1 + ((size_t)b * NTOK_ + base) * HID_ + c;
#pragma unroll
  for (int ky = 0; ky < 3; ++ky) {
    const int yy = hh + ky - 1;
    if ((unsigned)yy >= (unsigned)LH) continue;
#pragma unroll
    for (int kx = 0; kx < 3; ++kx) {
      const int xx = ww + kx - 1;
      if ((unsigned)xx >= (unsigned)LW) continue;
      z += yb[(size_t)(yy * LW + xx) * HID_] * dww[(ky * 3 + kx) * HID_ + c];
    }
  }
  y2[i] = f2bf(0.5f * z * (1.f + erff(z * 0.70710678118654752f)));
}

// ---------------------------------------------------------------------------
extern "C" void kernel_launch(void* const* d_in, const int* in_sizes, int n_in,
                              void* d_out, int out_size, void* d_ws, size_t ws_size,
                              hipStream_t stream) {
  const float* query  = (const float*)d_in[0];
  const float* ref    = (const float*)d_in[1];
  const float* feat   = (const float*)d_in[2];
  const float* qn_g   = (const float*)d_in[5];
  const float* qn_b   = (const float*)d_in[6];
  const float* fn_g   = (const float*)d_in[7];
  const float* fn_b   = (const float*)d_in[8];
  const float* W_off  = (const float*)d_in[9];
  const float* b_off  = (const float*)d_in[10];
  const float* W_attn = (const float*)d_in[11];
  const float* b_attn = (const float*)d_in[12];
  const float* W_val  = (const float*)d_in[13];
  const float* b_val  = (const float*)d_in[14];
  const float* W_out  = (const float*)d_in[15];
  const float* b_out  = (const float*)d_in[16];
  const float* ffn_g  = (const float*)d_in[17];
  const float* ffn_b  = (const float*)d_in[18];
  const float* fc1_w  = (const float*)d_in[19];
  const float* fc1_b  = (const float*)d_in[20];
  const float* dw_w   = (const float*)d_in[21];
  const float* dw_b   = (const float*)d_in[22];
  const float* fc2_w  = (const float*)d_in[23];
  const float* fc2_b  = (const float*)d_in[24];
  float* out = (float*)d_out;
  char* wsb = (char*)d_ws;

  // Workspace layout (bytes). taps aliases qn region (qn dead after oa-GEMM,
  // taps dead before xn is written into the same region).
  short* qn_xn = (short*)(wsb + 0);           // 43008*768 bf16
  int*   taps  = (int*)(wsb + 0);             // 258048*128 B alias
  short* vbf   = (short*)(wsb + 66060288);    // 8192*384 bf16
  float* oa    = (float*)(wsb + 72351744);    // 43008*72 fp32
  short* attnv = (short*)(wsb + 84738048);    // 43008*384 bf16
  float* y1    = (float*)(wsb + 84738048);    // alias (attnv dead) 43008*192 f32
  short* fnb   = (short*)(wsb + 117768192);   // 8192*768 bf16
  short* y2    = (short*)(wsb + 117768192);   // alias (fnb dead) 43008*192 bf16
  short* vt    = (short*)(wsb + 134283264);   // W_val^T  [384][768]
  short* oat   = (short*)(wsb + 134873088);   // [Woff|Wattn]^T [72][768]
  short* ot    = (short*)(wsb + 134983680);   // W_out^T  [768][384]
  short* f1t   = (short*)(wsb + 135573504);   // fc1^T    [192][768]
  short* f2t   = (short*)(wsb + 135868416);   // fc2^T    [768][192]

  // Weight transpose+convert (tiny)
  tconv<<<(768 * 384 + 255) / 256, 256, 0, stream>>>(W_val, vt, 768, 384, 0);
  tconv<<<(768 * 48 + 255) / 256, 256, 0, stream>>>(W_off, oat, 768, 48, 0);
  tconv<<<(768 * 24 + 255) / 256, 256, 0, stream>>>(W_attn, oat, 768, 24, 48);
  tconv<<<(384 * 768 + 255) / 256, 256, 0, stream>>>(W_out, ot, 384, 768, 0);
  tconv<<<(768 * 192 + 255) / 256, 256, 0, stream>>>(fc1_w, f1t, 768, 192, 0);
  tconv<<<(192 * 768 + 255) / 256, 256, 0, stream>>>(fc2_w, f2t, 192, 768, 0);

  // LN -> bf16
  ln_apply<<<MQ_, 256, 0, stream>>>(query, qn_g, qn_b, qn_xn);
  ln_apply<<<MF_, 256, 0, stream>>>(feat, fn_g, fn_b, fnb);

  // v = LN(feat) @ W_val + b_val  -> bf16 [8192 x 384]
  gemm_mfma<<<dim3(MF_ / 128, 3), 256, 0, stream>>>(
      fnb, vt, b_val, nullptr, nullptr, vbf, MF_, 384, 768);

  // [off|attn] = LN(q) @ [W_off|W_attn]  (biases folded into prep_taps)
  gemm_mfma<<<dim3(MQ_ / 128, 1), 256, 0, stream>>>(
      qn_xn, oat, nullptr, nullptr, oa, nullptr, MQ_, 72, 768);

  // build sampling taps (overwrites qn region — qn is dead now)
  prep_taps<<<(MQ_ * NH_ + 255) / 256, 256, 0, stream>>>(ref, b_off, b_attn, oa, taps);

  // gather + accumulate -> attnv (bf16)
  msda_sample2<<<MQ_ * NH_ * 16 / 256, 256, 0, stream>>>(vbf, taps, attnv);

  // x = attnv @ W_out + b_out + query -> d_out (fp32)
  gemm_mfma<<<dim3(MQ_ / 128, 6), 256, 0, stream>>>(
      attnv, ot, b_out, query, out, nullptr, MQ_, 768, 384);

  // xn = LN(x) bf16 (reuse qn/taps buffer — taps dead)
  ln_apply<<<MQ_, 256, 0, stream>>>(out, ffn_g, ffn_b, qn_xn);

  // y1 = xn @ fc1 + fc1_b (fp32, feeds conv)
  gemm_mfma<<<dim3(MQ_ / 128, 2), 256, 0, stream>>>(
      qn_xn, f1t, fc1_b, nullptr, y1, nullptr, MQ_, 192, 768);

  conv_gelu<<<(MQ_ * HID_ + 255) / 256, 256, 0, stream>>>(y1, dw_w, dw_b, y2);

  // out = x + y2 @ fc2 + fc2_b (in-place epilogue on d_out)
  gemm_mfma<<<dim3(MQ_ / 128, 6), 256, 0, stream>>>(
      y2, f2t, fc2_b, out, out, nullptr, MQ_, 768, 192);
}

// Round 4
// 705.738 us; speedup vs baseline: 2.1618x; 1.2536x over previous
//
#include <hip/hip_runtime.h>
#include <hip/hip_bf16.h>
#include <math.h>

// Fixed problem shapes
#define B_    8
#define DIM_  768
#define NH_   6
#define NP_   4
#define DV_   384
#define DH_   64
#define HID_  192
#define NTOK_ 5376
#define LIN_  1024
#define HH_   32
#define WW_   32
#define MQ_   (B_ * NTOK_)   // 43008
#define MF_   (B_ * LIN_)    // 8192

using fv4  = __attribute__((ext_vector_type(4))) float;
using bfv8 = __attribute__((ext_vector_type(8))) __bf16;
using sv8  = __attribute__((ext_vector_type(8))) short;
using sv4  = __attribute__((ext_vector_type(4))) short;

__device__ __forceinline__ short f2bf(float f) {
  union { float f; unsigned u; } v; v.f = f;
  unsigned r = v.u + 0x7FFFu + ((v.u >> 16) & 1u);   // RNE
  return (short)(r >> 16);
}
__device__ __forceinline__ float bf2f(short s) {
  union { unsigned u; float f; } v;
  v.u = ((unsigned)(unsigned short)s) << 16;
  return v.f;
}

// async global->LDS, 16B per lane (dest = wave-uniform base + lane*16)
__device__ __forceinline__ void gload16(const short* g, short* l) {
  __builtin_amdgcn_global_load_lds(
      (const __attribute__((address_space(1))) void*)g,
      (__attribute__((address_space(3))) void*)l, 16, 0, 0);
}

// ---------------------------------------------------------------------------
__device__ __forceinline__ float block_sum_f(float v, float* red, int nwaves) {
#pragma unroll
  for (int o = 32; o > 0; o >>= 1) v += __shfl_down(v, o, 64);
  int wid = threadIdx.x >> 6;
  int lane = threadIdx.x & 63;
  if (lane == 0) red[wid] = v;
  __syncthreads();
  float s = 0.f;
  for (int i = 0; i < nwaves; ++i) s += red[i];
  __syncthreads();
  return s;
}

// ---------------------------------------------------------------------------
__global__ __launch_bounds__(256) void ln_apply(const float* __restrict__ X,
                                                const float* __restrict__ g,
                                                const float* __restrict__ b,
                                                short* __restrict__ Y) {
  __shared__ float red[4];
  const int row = blockIdx.x;
  const float* xr = X + (size_t)row * DIM_;
  const int t = threadIdx.x;
  float x0 = xr[t], x1 = xr[t + 256], x2 = xr[t + 512];
  float s = block_sum_f(x0 + x1 + x2, red, 4);
  const float m = s * (1.f / 768.f);
  float d0 = x0 - m, d1 = x1 - m, d2 = x2 - m;
  float sq = block_sum_f(d0 * d0 + d1 * d1 + d2 * d2, red, 4);
  const float rs = rsqrtf(sq * (1.f / 768.f) + 1e-6f);
  short* yr = Y + (size_t)row * DIM_;
  yr[t]       = f2bf(d0 * rs * g[t]       + b[t]);
  yr[t + 256] = f2bf(d1 * rs * g[t + 256] + b[t + 256]);
  yr[t + 512] = f2bf(d2 * rs * g[t + 512] + b[t + 512]);
}

// ---------------------------------------------------------------------------
__global__ __launch_bounds__(256) void tconv(const float* __restrict__ src,
                                             short* __restrict__ dst,
                                             int K, int N, int rowOff) {
  const int i = blockIdx.x * 256 + threadIdx.x;
  if (i >= K * N) return;
  const int n = i / K, k = i % K;
  dst[(size_t)(n + rowOff) * K + k] = f2bf(src[(size_t)k * N + n]);
}

__global__ __launch_bounds__(256) void zfill(short* __restrict__ p, int n) {
  const int i = blockIdx.x * 256 + threadIdx.x;
  if (i < n) p[i] = 0;
}

// ---------------------------------------------------------------------------
// MFMA GEMM, 2-phase double-buffered global_load_lds pipeline.
// C[M,N] = A[M,K](bf16) @ Bt[N,K](bf16)^T + bias (+ addend), out fp32 or bf16.
// BM=BN=128, BK=64, 256 thr (4 waves, 2x2 of 64x64). M%128==0, K%64==0.
// LDS linear [128][64] with XOR swizzle (byte ^= (row&7)<<4) applied on the
// GLOBAL source address (global_load_lds writes linearly) and on ds_reads.
// XCD-aware bijective grid swizzle: all NT n-tiles of an m-tile on one XCD.
template <int NT>
__global__ __launch_bounds__(256) void gemm_mfma(
    const short* __restrict__ A, const short* __restrict__ Bt,
    const float* __restrict__ bias, const float* __restrict__ addend,
    float* __restrict__ C, short* __restrict__ Cb,
    int M, int N, int K) {
  __shared__ short As[2][8192];   // [128][64] x2 buffers, 16 KB each
  __shared__ short Bs[2][8192];

  // XCD swizzle: bid%8 = XCD (round-robin). Give XCD x m-tiles
  // [x*MT/8, (x+1)*MT/8), all NT n-tiles consecutive. Requires MT%8==0.
  const int bid = blockIdx.x;
  const int xcd = bid & 7;
  const int slot = bid >> 3;
  const int mpx = (M >> 7) >> 3;
  const int mt = xcd * mpx + slot / NT;
  const int nt = slot % NT;
  const int bm = mt << 7;
  const int bn = nt << 7;

  const int t = threadIdx.x;
  const int lane = t & 63;
  const int wid = t >> 6;
  const int wr = (wid >> 1) * 64;
  const int wc = (wid & 1) * 64;
  const int l15 = lane & 15;
  const int l4 = lane >> 4;
  const int lr = lane >> 3;                       // row-in-chunk 0..7
  const int cs = ((((lane & 7) << 4) ^ (lr << 4)) >> 1);  // swizzled src col (shorts)
  const int xorv = (l15 & 7) << 4;                // read-side XOR (bytes)

  // per-lane global base offsets (advance by 64 shorts per K-step)
  const short* pa0 = A + (size_t)(bm + wid * 32 + lr) * K + cs;
  const short* pb0 = Bt + (size_t)(bn + wid * 32 + lr) * K + cs;
  short* la0 = &As[0][wid * 2048];
  short* lb0 = &Bs[0][wid * 2048];
  short* la1 = &As[1][wid * 2048];
  short* lb1 = &Bs[1][wid * 2048];

  auto stage = [&](int buf, int kt) {
    const short* pa = pa0 + kt;
    const short* pb = pb0 + kt;
    short* la = buf ? la1 : la0;
    short* lb = buf ? lb1 : lb0;
#pragma unroll
    for (int i = 0; i < 4; ++i) {
      gload16(pa + (size_t)i * 8 * K, la + i * 512);
      gload16(pb + (size_t)i * 8 * K, lb + i * 512);
    }
  };

  fv4 acc[4][4] = {};
  const int nsteps = K >> 6;
  int cur = 0;
  stage(0, 0);
  __syncthreads();   // drains vmcnt(0) before first compute

  for (int tstep = 0; tstep < nsteps; ++tstep) {
    if (tstep + 1 < nsteps) stage(cur ^ 1, (tstep + 1) << 6);
    const short* Ab = As[cur];
    const short* Bb = Bs[cur];
#pragma unroll
    for (int kk = 0; kk < 2; ++kk) {
      const int cb = (l4 << 4) + (kk << 6);       // byte col in row
      const int co = (cb ^ xorv) >> 1;            // swizzled (shorts)
      bfv8 af[4], bfr[4];
#pragma unroll
      for (int m = 0; m < 4; ++m)
        af[m] = *(const bfv8*)&Ab[((wr + m * 16 + l15) << 6) + co];
#pragma unroll
      for (int n = 0; n < 4; ++n)
        bfr[n] = *(const bfv8*)&Bb[((wc + n * 16 + l15) << 6) + co];
#pragma unroll
      for (int m = 0; m < 4; ++m)
#pragma unroll
        for (int n = 0; n < 4; ++n)
          acc[m][n] = __builtin_amdgcn_mfma_f32_16x16x32_bf16(
              bfr[n], af[m], acc[m][n], 0, 0, 0);   // swapped: lane holds 4 cols
    }
    __syncthreads();   // next buffer staged + this buffer free
    cur ^= 1;
  }

  // Swapped-operand C/D: row = bm+wr+m*16+(lane&15),
  //                      col = bn+wc+n*16+(lane>>4)*4 + reg  (4 contiguous)
  const int rb = bm + wr + l15;
  const int cbase = bn + wc + l4 * 4;
#pragma unroll
  for (int n = 0; n < 4; ++n) {
    const int colb = cbase + n * 16;
    if (colb >= N) continue;                      // N%4==0 so no straddle
    fv4 bv = {};
    if (bias) bv = *(const fv4*)&bias[colb];
#pragma unroll
    for (int m = 0; m < 4; ++m) {
      const int row = rb + m * 16;
      const size_t o = (size_t)row * N + colb;
      fv4 vv = acc[m][n] + bv;
      if (addend) vv += *(const fv4*)&addend[o];
      if (C) {
        *(fv4*)&C[o] = vv;
      } else {
        sv4 r;
        r[0] = f2bf(vv[0]); r[1] = f2bf(vv[1]);
        r[2] = f2bf(vv[2]); r[3] = f2bf(vv[3]);
        *(sv4*)&Cb[o] = r;
      }
    }
  }
}

// ---------------------------------------------------------------------------
// prep_taps: one thread per (token,head): biases + grid + softmax -> 16 taps.
__global__ __launch_bounds__(256) void prep_taps(
    const float* __restrict__ ref, const float* __restrict__ boff,
    const float* __restrict__ battn, const float* __restrict__ oa,
    int* __restrict__ taps) {
  const int i = blockIdx.x * 256 + threadIdx.x;
  if (i >= MQ_ * NH_) return;
  const int row = i / NH_, head = i % NH_;
  const float rx = ref[(size_t)row * 2 + 0];
  const float ry = ref[(size_t)row * 2 + 1];
  const float* o = oa + (size_t)row * 72 + head * 8;
  const float* ap = oa + (size_t)row * 72 + 48 + head * 4;
  float l0 = ap[0] + battn[head * 4 + 0];
  float l1 = ap[1] + battn[head * 4 + 1];
  float l2 = ap[2] + battn[head * 4 + 2];
  float l3 = ap[3] + battn[head * 4 + 3];
  float mx = fmaxf(fmaxf(l0, l1), fmaxf(l2, l3));
  float e0 = expf(l0 - mx), e1 = expf(l1 - mx);
  float e2 = expf(l2 - mx), e3 = expf(l3 - mx);
  float sinv = 1.f / (e0 + e1 + e2 + e3);
  float aw[4] = {e0 * sinv, e1 * sinv, e2 * sinv, e3 * sinv};

  int st[32];
  int k = 0;
#pragma unroll
  for (int p = 0; p < 4; ++p) {
    const float lx = rx + (o[p * 2 + 0] + boff[head * 8 + p * 2 + 0]) * (1.f / 32.f);
    const float ly = ry + (o[p * 2 + 1] + boff[head * 8 + p * 2 + 1]) * (1.f / 32.f);
    const float x = lx * (float)WW_ - 0.5f;
    const float y = ly * (float)HH_ - 0.5f;
    const float x0f = floorf(x), y0f = floorf(y);
    const float wx = x - x0f, wy = y - y0f;
    const int x0 = (int)x0f, y0 = (int)y0f;
    const float a = aw[p];
#pragma unroll
    for (int dy = 0; dy < 2; ++dy) {
      const int yi = y0 + dy;
      const float wyy = dy ? wy : 1.f - wy;
#pragma unroll
      for (int dx = 0; dx < 2; ++dx) {
        const int xi = x0 + dx;
        const float wxx = dx ? wx : 1.f - wx;
        const bool valid = ((unsigned)xi < (unsigned)WW_) & ((unsigned)yi < (unsigned)HH_);
        const int xc = min(max(xi, 0), WW_ - 1);
        const int yc = min(max(yi, 0), HH_ - 1);
        st[k++] = (yc * WW_ + xc) * DV_;
        float w = a * wxx * wyy;
        st[k++] = __float_as_int(valid ? w : 0.f);
      }
    }
  }
  int4* dst = (int4*)(taps + (size_t)i * 32);
#pragma unroll
  for (int j = 0; j < 8; ++j)
    dst[j] = make_int4(st[4 * j], st[4 * j + 1], st[4 * j + 2], st[4 * j + 3]);
}

// ---------------------------------------------------------------------------
__global__ __launch_bounds__(256) void msda_sample2(const short* __restrict__ v,
                                                    const int* __restrict__ taps,
                                                    short* __restrict__ outv) {
  const int gid = blockIdx.x * 256 + threadIdx.x;
  const int pair = gid >> 4;
  const int ch0 = (gid & 15) * 4;
  const int row = pair / NH_;
  const int head = pair - row * NH_;
  const int b = row / NTOK_;
  const short* vb = v + (size_t)b * LIN_ * DV_ + head * DH_ + ch0;
  const int4* tp = (const int4*)(taps + (size_t)pair * 32);
  float a0 = 0.f, a1 = 0.f, a2 = 0.f, a3 = 0.f;
#pragma unroll
  for (int j = 0; j < 8; ++j) {
    int4 pr = tp[j];
    {
      sv4 val = *(const sv4*)&vb[pr.x];
      const float w = __int_as_float(pr.y);
      a0 += w * bf2f(val[0]); a1 += w * bf2f(val[1]);
      a2 += w * bf2f(val[2]); a3 += w * bf2f(val[3]);
    }
    {
      sv4 val = *(const sv4*)&vb[pr.z];
      const float w = __int_as_float(pr.w);
      a0 += w * bf2f(val[0]); a1 += w * bf2f(val[1]);
      a2 += w * bf2f(val[2]); a3 += w * bf2f(val[3]);
    }
  }
  sv4 r;
  r[0] = f2bf(a0); r[1] = f2bf(a1); r[2] = f2bf(a2); r[3] = f2bf(a3);
  *(sv4*)&outv[(size_t)gid * 4] = r;
}

// ---------------------------------------------------------------------------
// Depthwise 3x3 + bias + exact GELU. Input y1 bf16, output bf16.
__global__ __launch_bounds__(256) void conv_gelu(const short* __restrict__ y1,
                                                 const float* __restrict__ dww,
                                                 const float* __restrict__ dwb,
                                                 short* __restrict__ y2) {
  const int i = blockIdx.x * 256 + threadIdx.x;
  if (i >= B_ * NTOK_ * HID_) return;
  const int c = i % HID_;
  const int tmp = i / HID_;
  const int tok = tmp % NTOK_;
  const int b = tmp / NTOK_;
  int base, LH, LW;
  if (tok < 4096)      { base = 0;    LH = 64; LW = 64; }
  else if (tok < 5120) { base = 4096; LH = 32; LW = 32; }
  else                 { base = 5120; LH = 16; LW = 16; }
  const int pos = tok - base;
  const int hh = pos / LW, ww = pos % LW;
  float z = dwb[c];
  const short* yb = y1 + ((size_t)b * NTOK_ + base) * HID_ + c;
#pragma unroll
  for (int ky = 0; ky < 3; ++ky) {
    const int yy = hh + ky - 1;
    if ((unsigned)yy >= (unsigned)LH) continue;
#pragma unroll
    for (int kx = 0; kx < 3; ++kx) {
      const int xx = ww + kx - 1;
      if ((unsigned)xx >= (unsigned)LW) continue;
      z += bf2f(yb[(size_t)(yy * LW + xx) * HID_]) * dww[(ky * 3 + kx) * HID_ + c];
    }
  }
  y2[i] = f2bf(0.5f * z * (1.f + erff(z * 0.70710678118654752f)));
}

// ---------------------------------------------------------------------------
extern "C" void kernel_launch(void* const* d_in, const int* in_sizes, int n_in,
                              void* d_out, int out_size, void* d_ws, size_t ws_size,
                              hipStream_t stream) {
  const float* query  = (const float*)d_in[0];
  const float* ref    = (const float*)d_in[1];
  const float* feat   = (const float*)d_in[2];
  const float* qn_g   = (const float*)d_in[5];
  const float* qn_b   = (const float*)d_in[6];
  const float* fn_g   = (const float*)d_in[7];
  const float* fn_b   = (const float*)d_in[8];
  const float* W_off  = (const float*)d_in[9];
  const float* b_off  = (const float*)d_in[10];
  const float* W_attn = (const float*)d_in[11];
  const float* b_attn = (const float*)d_in[12];
  const float* W_val  = (const float*)d_in[13];
  const float* b_val  = (const float*)d_in[14];
  const float* W_out  = (const float*)d_in[15];
  const float* b_out  = (const float*)d_in[16];
  const float* ffn_g  = (const float*)d_in[17];
  const float* ffn_b  = (const float*)d_in[18];
  const float* fc1_w  = (const float*)d_in[19];
  const float* fc1_b  = (const float*)d_in[20];
  const float* dw_w   = (const float*)d_in[21];
  const float* dw_b   = (const float*)d_in[22];
  const float* fc2_w  = (const float*)d_in[23];
  const float* fc2_b  = (const float*)d_in[24];
  float* out = (float*)d_out;
  char* wsb = (char*)d_ws;

  // Workspace layout (bytes). Aliases annotated; peak 136,052,736 B.
  short* qn_xn = (short*)(wsb + 0);           // 43008*768 bf16 (qn; later xn)
  int*   taps  = (int*)(wsb + 0);             // alias (qn dead after oa-GEMM)
  short* vbf   = (short*)(wsb + 66060288);    // 8192*384 bf16
  float* oa    = (float*)(wsb + 72351744);    // 43008*72 fp32
  short* attnv = (short*)(wsb + 84738048);    // 43008*384 bf16
  short* y1b   = (short*)(wsb + 84738048);    // alias (attnv dead) 43008*192 bf16
  short* fnb   = (short*)(wsb + 117768192);   // 8192*768 bf16
  short* y2    = (short*)(wsb + 117768192);   // alias (fnb dead) 43008*192 bf16
  short* oat   = (short*)(wsb + 130351104);   // [128][768] padded (zero rows 72+)
  short* vt    = (short*)(wsb + 134283264);   // W_val^T  [384][768]
  short* ot    = (short*)(wsb + 134873088);   // W_out^T  [768][384]
  short* f1t   = (short*)(wsb + 135462912);   // fc1^T    [192][768]
  short* f2t   = (short*)(wsb + 135757824);   // fc2^T    [768][192]

  // Weight prep
  zfill<<<(128 * 768 + 255) / 256, 256, 0, stream>>>(oat, 128 * 768);
  tconv<<<(768 * 384 + 255) / 256, 256, 0, stream>>>(W_val, vt, 768, 384, 0);
  tconv<<<(768 * 48 + 255) / 256, 256, 0, stream>>>(W_off, oat, 768, 48, 0);
  tconv<<<(768 * 24 + 255) / 256, 256, 0, stream>>>(W_attn, oat, 768, 24, 48);
  tconv<<<(384 * 768 + 255) / 256, 256, 0, stream>>>(W_out, ot, 384, 768, 0);
  tconv<<<(768 * 192 + 255) / 256, 256, 0, stream>>>(fc1_w, f1t, 768, 192, 0);
  tconv<<<(192 * 768 + 255) / 256, 256, 0, stream>>>(fc2_w, f2t, 192, 768, 0);

  // LN -> bf16
  ln_apply<<<MQ_, 256, 0, stream>>>(query, qn_g, qn_b, qn_xn);
  ln_apply<<<MF_, 256, 0, stream>>>(feat, fn_g, fn_b, fnb);

  // v = LN(feat) @ W_val + b_val -> bf16 [8192 x 384]
  gemm_mfma<3><<<(MF_ / 128) * 3, 256, 0, stream>>>(
      fnb, vt, b_val, nullptr, nullptr, vbf, MF_, 384, 768);

  // [off|attn] = LN(q) @ [W_off|W_attn] -> fp32 [43008 x 72]
  gemm_mfma<1><<<(MQ_ / 128) * 1, 256, 0, stream>>>(
      qn_xn, oat, nullptr, nullptr, oa, nullptr, MQ_, 72, 768);

  prep_taps<<<(MQ_ * NH_ + 255) / 256, 256, 0, stream>>>(ref, b_off, b_attn, oa, taps);

  msda_sample2<<<MQ_ * NH_ * 16 / 256, 256, 0, stream>>>(vbf, taps, attnv);

  // x = attnv @ W_out + b_out + query -> d_out (fp32)
  gemm_mfma<6><<<(MQ_ / 128) * 6, 256, 0, stream>>>(
      attnv, ot, b_out, query, out, nullptr, MQ_, 768, 384);

  // xn = LN(x) -> bf16 (reuse qn/taps region)
  ln_apply<<<MQ_, 256, 0, stream>>>(out, ffn_g, ffn_b, qn_xn);

  // y1 = xn @ fc1 + fc1_b -> bf16
  gemm_mfma<2><<<(MQ_ / 128) * 2, 256, 0, stream>>>(
      qn_xn, f1t, fc1_b, nullptr, nullptr, y1b, MQ_, 192, 768);

  conv_gelu<<<(MQ_ * HID_ + 255) / 256, 256, 0, stream>>>(y1b, dw_w, dw_b, y2);

  // out = x + y2 @ fc2 + fc2_b (in-place epilogue on d_out)
  gemm_mfma<6><<<(MQ_ / 128) * 6, 256, 0, stream>>>(
      y2, f2t, fc2_b, out, out, nullptr, MQ_, 768, 192);
}

// Round 5
// 697.045 us; speedup vs baseline: 2.1888x; 1.0125x over previous
//
#include <hip/hip_runtime.h>
#include <hip/hip_bf16.h>
#include <math.h>

// Fixed problem shapes
#define B_    8
#define DIM_  768
#define NH_   6
#define NP_   4
#define DV_   384
#define DH_   64
#define HID_  192
#define NTOK_ 5376
#define LIN_  1024
#define HH_   32
#define WW_   32
#define MQ_   (B_ * NTOK_)   // 43008
#define MF_   (B_ * LIN_)    // 8192

using fv4  = __attribute__((ext_vector_type(4))) float;
using bfv8 = __attribute__((ext_vector_type(8))) __bf16;
using sv8  = __attribute__((ext_vector_type(8))) short;
using sv4  = __attribute__((ext_vector_type(4))) short;

__device__ __forceinline__ short f2bf(float f) {
  union { float f; unsigned u; } v; v.f = f;
  unsigned r = v.u + 0x7FFFu + ((v.u >> 16) & 1u);   // RNE
  return (short)(r >> 16);
}
__device__ __forceinline__ float bf2f(short s) {
  union { unsigned u; float f; } v;
  v.u = ((unsigned)(unsigned short)s) << 16;
  return v.f;
}

// async global->LDS, 16B per lane (dest = wave-uniform base + lane*16)
__device__ __forceinline__ void gload16(const short* g, short* l) {
  __builtin_amdgcn_global_load_lds(
      (const __attribute__((address_space(1))) void*)g,
      (__attribute__((address_space(3))) void*)l, 16, 0, 0);
}

// ---------------------------------------------------------------------------
__device__ __forceinline__ float block_sum_f(float v, float* red, int nwaves) {
#pragma unroll
  for (int o = 32; o > 0; o >>= 1) v += __shfl_down(v, o, 64);
  int wid = threadIdx.x >> 6;
  int lane = threadIdx.x & 63;
  if (lane == 0) red[wid] = v;
  __syncthreads();
  float s = 0.f;
  for (int i = 0; i < nwaves; ++i) s += red[i];
  __syncthreads();
  return s;
}

// ---------------------------------------------------------------------------
// LayerNorm -> bf16, float4 loads: 192 threads x 4 floats = 768.
__global__ __launch_bounds__(192) void ln_apply(const float* __restrict__ X,
                                                const float* __restrict__ g,
                                                const float* __restrict__ b,
                                                short* __restrict__ Y) {
  __shared__ float red[3];
  const int row = blockIdx.x;
  const int t = threadIdx.x;
  const fv4 x = ((const fv4*)(X + (size_t)row * DIM_))[t];
  float s = block_sum_f(x[0] + x[1] + x[2] + x[3], red, 3);
  const float m = s * (1.f / 768.f);
  fv4 d = x - m;
  float sq = block_sum_f(d[0] * d[0] + d[1] * d[1] + d[2] * d[2] + d[3] * d[3],
                         red, 3);
  const float rs = rsqrtf(sq * (1.f / 768.f) + 1e-6f);
  const fv4 g4 = ((const fv4*)g)[t];
  const fv4 b4 = ((const fv4*)b)[t];
  sv4 r;
  r[0] = f2bf(d[0] * rs * g4[0] + b4[0]);
  r[1] = f2bf(d[1] * rs * g4[1] + b4[1]);
  r[2] = f2bf(d[2] * rs * g4[2] + b4[2]);
  r[3] = f2bf(d[3] * rs * g4[3] + b4[3]);
  ((sv4*)(Y + (size_t)row * DIM_))[t] = r;
}

// ---------------------------------------------------------------------------
__global__ __launch_bounds__(256) void tconv(const float* __restrict__ src,
                                             short* __restrict__ dst,
                                             int K, int N, int rowOff) {
  const int i = blockIdx.x * 256 + threadIdx.x;
  if (i >= K * N) return;
  const int n = i / K, k = i % K;
  dst[(size_t)(n + rowOff) * K + k] = f2bf(src[(size_t)k * N + n]);
}

__global__ __launch_bounds__(256) void zfill(short* __restrict__ p, int n) {
  const int i = blockIdx.x * 256 + threadIdx.x;
  if (i < n) p[i] = 0;
}

// ---------------------------------------------------------------------------
// MFMA GEMM, 2-phase double-buffered global_load_lds pipeline.
// BM=BN=64, BK=64, 256 thr (4 waves, 2x2 of 32x32). 32 KB LDS -> 5 blocks/CU.
// LDS linear [64][64] bf16 (128 B rows), XOR swizzle (byte ^= (row&7)<<4)
// pre-applied on the GLOBAL source address, applied again on ds_reads.
// XCD-aware bijective grid swizzle (MT%8==0 guaranteed by shapes).
template <int NT>
__global__ __launch_bounds__(256) void gemm_mfma(
    const short* __restrict__ A, const short* __restrict__ Bt,
    const float* __restrict__ bias, const float* __restrict__ addend,
    float* __restrict__ C, short* __restrict__ Cb,
    int M, int N, int K) {
  __shared__ short As[2][4096];   // [64][64] per buffer, 8 KB
  __shared__ short Bs[2][4096];

  const int bid = blockIdx.x;
  const int xcd = bid & 7;
  const int slot = bid >> 3;
  const int mpx = (M >> 6) >> 3;
  const int mt = xcd * mpx + slot / NT;
  const int nt = slot % NT;
  const int bm = mt << 6;
  const int bn = nt << 6;

  const int t = threadIdx.x;
  const int lane = t & 63;
  const int wid = t >> 6;
  const int wr = (wid >> 1) * 32;
  const int wc = (wid & 1) * 32;
  const int l15 = lane & 15;
  const int l4 = lane >> 4;
  const int lr = lane >> 3;                       // row 0..7 in 8-row group
  const int cs = ((((lane & 7) << 4) ^ (lr << 4)) >> 1);  // swizzled src col
  const int xorv = (l15 & 7) << 4;                // read-side XOR (bytes)

  const short* pa0 = A + (size_t)(bm + wid * 8 + lr) * K + cs;
  const short* pb0 = Bt + (size_t)(bn + wid * 8 + lr) * K + cs;

  auto stage = [&](int buf, int kt) {
    const short* pa = pa0 + kt;
    const short* pb = pb0 + kt;
    short* la = &As[buf][wid * 512];
    short* lb = &Bs[buf][wid * 512];
#pragma unroll
    for (int i = 0; i < 2; ++i) {   // 2 x 32 rows
      gload16(pa + (size_t)(i * 32) * K, la + i * 2048);
      gload16(pb + (size_t)(i * 32) * K, lb + i * 2048);
    }
  };

  fv4 acc[2][2] = {};
  const int nsteps = K >> 6;
  int cur = 0;
  stage(0, 0);
  __syncthreads();

  for (int tstep = 0; tstep < nsteps; ++tstep) {
    if (tstep + 1 < nsteps) stage(cur ^ 1, (tstep + 1) << 6);
    const short* Ab = As[cur];
    const short* Bb = Bs[cur];
#pragma unroll
    for (int kk = 0; kk < 2; ++kk) {
      const int cb = (l4 << 4) + (kk << 6);
      const int co = (cb ^ xorv) >> 1;
      bfv8 af[2], bfr[2];
#pragma unroll
      for (int m = 0; m < 2; ++m)
        af[m] = *(const bfv8*)&Ab[((wr + m * 16 + l15) << 6) + co];
#pragma unroll
      for (int n = 0; n < 2; ++n)
        bfr[n] = *(const bfv8*)&Bb[((wc + n * 16 + l15) << 6) + co];
#pragma unroll
      for (int m = 0; m < 2; ++m)
#pragma unroll
        for (int n = 0; n < 2; ++n)
          acc[m][n] = __builtin_amdgcn_mfma_f32_16x16x32_bf16(
              bfr[n], af[m], acc[m][n], 0, 0, 0);   // swapped: lane holds 4 cols
    }
    __syncthreads();
    cur ^= 1;
  }

  // Swapped-operand C/D: row = bm+wr+m*16+(lane&15),
  //                      col = bn+wc+n*16+(lane>>4)*4 + reg (4 contiguous)
  const int rb = bm + wr + l15;
  const int cbase = bn + wc + l4 * 4;
#pragma unroll
  for (int n = 0; n < 2; ++n) {
    const int colb = cbase + n * 16;
    if (colb >= N) continue;
    fv4 bv = {};
    if (bias) bv = *(const fv4*)&bias[colb];
#pragma unroll
    for (int m = 0; m < 2; ++m) {
      const int row = rb + m * 16;
      const size_t o = (size_t)row * N + colb;
      fv4 vv = acc[m][n] + bv;
      if (addend) vv += *(const fv4*)&addend[o];
      if (C) {
        *(fv4*)&C[o] = vv;
      } else {
        sv4 r;
        r[0] = f2bf(vv[0]); r[1] = f2bf(vv[1]);
        r[2] = f2bf(vv[2]); r[3] = f2bf(vv[3]);
        *(sv4*)&Cb[o] = r;
      }
    }
  }
}

// ---------------------------------------------------------------------------
// prep_taps: one thread per (token,head): biases + grid + softmax -> 16 taps.
__global__ __launch_bounds__(256) void prep_taps(
    const float* __restrict__ ref, const float* __restrict__ boff,
    const float* __restrict__ battn, const float* __restrict__ oa,
    int* __restrict__ taps) {
  const int i = blockIdx.x * 256 + threadIdx.x;
  if (i >= MQ_ * NH_) return;
  const int row = i / NH_, head = i % NH_;
  const float rx = ref[(size_t)row * 2 + 0];
  const float ry = ref[(size_t)row * 2 + 1];
  const float* o = oa + (size_t)row * 72 + head * 8;
  const float* ap = oa + (size_t)row * 72 + 48 + head * 4;
  float l0 = ap[0] + battn[head * 4 + 0];
  float l1 = ap[1] + battn[head * 4 + 1];
  float l2 = ap[2] + battn[head * 4 + 2];
  float l3 = ap[3] + battn[head * 4 + 3];
  float mx = fmaxf(fmaxf(l0, l1), fmaxf(l2, l3));
  float e0 = expf(l0 - mx), e1 = expf(l1 - mx);
  float e2 = expf(l2 - mx), e3 = expf(l3 - mx);
  float sinv = 1.f / (e0 + e1 + e2 + e3);
  float aw[4] = {e0 * sinv, e1 * sinv, e2 * sinv, e3 * sinv};

  int st[32];
  int k = 0;
#pragma unroll
  for (int p = 0; p < 4; ++p) {
    const float lx = rx + (o[p * 2 + 0] + boff[head * 8 + p * 2 + 0]) * (1.f / 32.f);
    const float ly = ry + (o[p * 2 + 1] + boff[head * 8 + p * 2 + 1]) * (1.f / 32.f);
    const float x = lx * (float)WW_ - 0.5f;
    const float y = ly * (float)HH_ - 0.5f;
    const float x0f = floorf(x), y0f = floorf(y);
    const float wx = x - x0f, wy = y - y0f;
    const int x0 = (int)x0f, y0 = (int)y0f;
    const float a = aw[p];
#pragma unroll
    for (int dy = 0; dy < 2; ++dy) {
      const int yi = y0 + dy;
      const float wyy = dy ? wy : 1.f - wy;
#pragma unroll
      for (int dx = 0; dx < 2; ++dx) {
        const int xi = x0 + dx;
        const float wxx = dx ? wx : 1.f - wx;
        const bool valid = ((unsigned)xi < (unsigned)WW_) & ((unsigned)yi < (unsigned)HH_);
        const int xc = min(max(xi, 0), WW_ - 1);
        const int yc = min(max(yi, 0), HH_ - 1);
        st[k++] = (yc * WW_ + xc) * DV_;
        float w = a * wxx * wyy;
        st[k++] = __float_as_int(valid ? w : 0.f);
      }
    }
  }
  int4* dst = (int4*)(taps + (size_t)i * 32);
#pragma unroll
  for (int j = 0; j < 8; ++j)
    dst[j] = make_int4(st[4 * j], st[4 * j + 1], st[4 * j + 2], st[4 * j + 3]);
}

// ---------------------------------------------------------------------------
__global__ __launch_bounds__(256) void msda_sample2(const short* __restrict__ v,
                                                    const int* __restrict__ taps,
                                                    short* __restrict__ outv) {
  const int gid = blockIdx.x * 256 + threadIdx.x;
  const int pair = gid >> 4;
  const int ch0 = (gid & 15) * 4;
  const int row = pair / NH_;
  const int head = pair - row * NH_;
  const int b = row / NTOK_;
  const short* vb = v + (size_t)b * LIN_ * DV_ + head * DH_ + ch0;
  const int4* tp = (const int4*)(taps + (size_t)pair * 32);
  float a0 = 0.f, a1 = 0.f, a2 = 0.f, a3 = 0.f;
#pragma unroll
  for (int j = 0; j < 8; ++j) {
    int4 pr = tp[j];
    {
      sv4 val = *(const sv4*)&vb[pr.x];
      const float w = __int_as_float(pr.y);
      a0 += w * bf2f(val[0]); a1 += w * bf2f(val[1]);
      a2 += w * bf2f(val[2]); a3 += w * bf2f(val[3]);
    }
    {
      sv4 val = *(const sv4*)&vb[pr.z];
      const float w = __int_as_float(pr.w);
      a0 += w * bf2f(val[0]); a1 += w * bf2f(val[1]);
      a2 += w * bf2f(val[2]); a3 += w * bf2f(val[3]);
    }
  }
  sv4 r;
  r[0] = f2bf(a0); r[1] = f2bf(a1); r[2] = f2bf(a2); r[3] = f2bf(a3);
  *(sv4*)&outv[(size_t)gid * 4] = r;
}

// ---------------------------------------------------------------------------
// Depthwise 3x3 + bias + exact GELU. Input y1 bf16, output bf16.
__global__ __launch_bounds__(256) void conv_gelu(const short* __restrict__ y1,
                                                 const float* __restrict__ dww,
                                                 const float* __restrict__ dwb,
                                                 short* __restrict__ y2) {
  const int i = blockIdx.x * 256 + threadIdx.x;
  if (i >= B_ * NTOK_ * HID_) return;
  const int c = i % HID_;
  const int tmp = i / HID_;
  const int tok = tmp % NTOK_;
  const int b = tmp / NTOK_;
  int base, LH, LW;
  if (tok < 4096)      { base = 0;    LH = 64; LW = 64; }
  else if (tok < 5120) { base = 4096; LH = 32; LW = 32; }
  else                 { base = 5120; LH = 16; LW = 16; }
  const int pos = tok - base;
  const int hh = pos / LW, ww = pos % LW;
  float z = dwb[c];
  const short* yb = y1 + ((size_t)b * NTOK_ + base) * HID_ + c;
#pragma unroll
  for (int ky = 0; ky < 3; ++ky) {
    const int yy = hh + ky - 1;
    if ((unsigned)yy >= (unsigned)LH) continue;
#pragma unroll
    for (int kx = 0; kx < 3; ++kx) {
      const int xx = ww + kx - 1;
      if ((unsigned)xx >= (unsigned)LW) continue;
      z += bf2f(yb[(size_t)(yy * LW + xx) * HID_]) * dww[(ky * 3 + kx) * HID_ + c];
    }
  }
  y2[i] = f2bf(0.5f * z * (1.f + erff(z * 0.70710678118654752f)));
}

// ---------------------------------------------------------------------------
extern "C" void kernel_launch(void* const* d_in, const int* in_sizes, int n_in,
                              void* d_out, int out_size, void* d_ws, size_t ws_size,
                              hipStream_t stream) {
  const float* query  = (const float*)d_in[0];
  const float* ref    = (const float*)d_in[1];
  const float* feat   = (const float*)d_in[2];
  const float* qn_g   = (const float*)d_in[5];
  const float* qn_b   = (const float*)d_in[6];
  const float* fn_g   = (const float*)d_in[7];
  const float* fn_b   = (const float*)d_in[8];
  const float* W_off  = (const float*)d_in[9];
  const float* b_off  = (const float*)d_in[10];
  const float* W_attn = (const float*)d_in[11];
  const float* b_attn = (const float*)d_in[12];
  const float* W_val  = (const float*)d_in[13];
  const float* b_val  = (const float*)d_in[14];
  const float* W_out  = (const float*)d_in[15];
  const float* b_out  = (const float*)d_in[16];
  const float* ffn_g  = (const float*)d_in[17];
  const float* ffn_b  = (const float*)d_in[18];
  const float* fc1_w  = (const float*)d_in[19];
  const float* fc1_b  = (const float*)d_in[20];
  const float* dw_w   = (const float*)d_in[21];
  const float* dw_b   = (const float*)d_in[22];
  const float* fc2_w  = (const float*)d_in[23];
  const float* fc2_b  = (const float*)d_in[24];
  float* out = (float*)d_out;
  char* wsb = (char*)d_ws;

  // Workspace layout (bytes). Aliases annotated; peak ~136 MB.
  short* qn_xn = (short*)(wsb + 0);           // 43008*768 bf16 (qn; later xn)
  int*   taps  = (int*)(wsb + 0);             // alias (qn dead after oa-GEMM)
  short* vbf   = (short*)(wsb + 66060288);    // 8192*384 bf16
  float* oa    = (float*)(wsb + 72351744);    // 43008*72 fp32
  short* attnv = (short*)(wsb + 84738048);    // 43008*384 bf16
  short* y1b   = (short*)(wsb + 84738048);    // alias (attnv dead) 43008*192 bf16
  short* fnb   = (short*)(wsb + 117768192);   // 8192*768 bf16
  short* y2    = (short*)(wsb + 117768192);   // alias (fnb dead) 43008*192 bf16
  short* oat   = (short*)(wsb + 130351104);   // [128][768] padded (zero rows 72+)
  short* vt    = (short*)(wsb + 134283264);   // W_val^T  [384][768]
  short* ot    = (short*)(wsb + 134873088);   // W_out^T  [768][384]
  short* f1t   = (short*)(wsb + 135462912);   // fc1^T    [192][768]
  short* f2t   = (short*)(wsb + 135757824);   // fc2^T    [768][192]

  // Weight prep
  zfill<<<(128 * 768 + 255) / 256, 256, 0, stream>>>(oat, 128 * 768);
  tconv<<<(768 * 384 + 255) / 256, 256, 0, stream>>>(W_val, vt, 768, 384, 0);
  tconv<<<(768 * 48 + 255) / 256, 256, 0, stream>>>(W_off, oat, 768, 48, 0);
  tconv<<<(768 * 24 + 255) / 256, 256, 0, stream>>>(W_attn, oat, 768, 24, 48);
  tconv<<<(384 * 768 + 255) / 256, 256, 0, stream>>>(W_out, ot, 384, 768, 0);
  tconv<<<(768 * 192 + 255) / 256, 256, 0, stream>>>(fc1_w, f1t, 768, 192, 0);
  tconv<<<(192 * 768 + 255) / 256, 256, 0, stream>>>(fc2_w, f2t, 192, 768, 0);

  // LN -> bf16
  ln_apply<<<MQ_, 192, 0, stream>>>(query, qn_g, qn_b, qn_xn);
  ln_apply<<<MF_, 192, 0, stream>>>(feat, fn_g, fn_b, fnb);

  // v = LN(feat) @ W_val + b_val -> bf16 [8192 x 384]
  gemm_mfma<6><<<(MF_ / 64) * 6, 256, 0, stream>>>(
      fnb, vt, b_val, nullptr, nullptr, vbf, MF_, 384, 768);

  // [off|attn] = LN(q) @ [W_off|W_attn] -> fp32 [43008 x 72]
  gemm_mfma<2><<<(MQ_ / 64) * 2, 256, 0, stream>>>(
      qn_xn, oat, nullptr, nullptr, oa, nullptr, MQ_, 72, 768);

  prep_taps<<<(MQ_ * NH_ + 255) / 256, 256, 0, stream>>>(ref, b_off, b_attn, oa, taps);

  msda_sample2<<<MQ_ * NH_ * 16 / 256, 256, 0, stream>>>(vbf, taps, attnv);

  // x = attnv @ W_out + b_out + query -> d_out (fp32)
  gemm_mfma<12><<<(MQ_ / 64) * 12, 256, 0, stream>>>(
      attnv, ot, b_out, query, out, nullptr, MQ_, 768, 384);

  // xn = LN(x) -> bf16 (reuse qn/taps region)
  ln_apply<<<MQ_, 192, 0, stream>>>(out, ffn_g, ffn_b, qn_xn);

  // y1 = xn @ fc1 + fc1_b -> bf16
  gemm_mfma<3><<<(MQ_ / 64) * 3, 256, 0, stream>>>(
      qn_xn, f1t, fc1_b, nullptr, nullptr, y1b, MQ_, 192, 768);

  conv_gelu<<<(MQ_ * HID_ + 255) / 256, 256, 0, stream>>>(y1b, dw_w, dw_b, y2);

  // out = x + y2 @ fc2 + fc2_b (in-place epilogue on d_out)
  gemm_mfma<12><<<(MQ_ / 64) * 12, 256, 0, stream>>>(
      y2, f2t, fc2_b, out, out, nullptr, MQ_, 768, 192);
}